// Round 5
// baseline (283.773 us; speedup 1.0000x reference)
//
#include <hip/hip_runtime.h>
#include <hip/hip_bf16.h>

typedef unsigned short u16;
typedef __bf16 bf16x8 __attribute__((ext_vector_type(8)));
typedef float f32x4 __attribute__((ext_vector_type(4)));

#define NTOK 32768   // B*S = 8*4096
#define DIM  512
#define KC   4096

__device__ __forceinline__ u16 f2b(float f) {
  __hip_bfloat16 h = __float2bfloat16(f);
  return *reinterpret_cast<u16*>(&h);
}

__device__ __forceinline__ void gload_lds16(const void* g, void* l) {
  __builtin_amdgcn_global_load_lds(
      (__attribute__((address_space(1))) void*)g,
      (__attribute__((address_space(3))) void*)l,
      16, 0, 0);
}

// ---------------- prep: fp32 -> bf16 conversion (8 elems/thread) -------------
__global__ void cvt8(const float* __restrict__ in, u16* __restrict__ out, int n8) {
  int i = blockIdx.x * blockDim.x + threadIdx.x;
  if (i >= n8) return;
  const float4* p = reinterpret_cast<const float4*>(in) + 2 * (size_t)i;
  float4 a = p[0], b = p[1];
  uint4 v;
  v.x = (unsigned)f2b(a.x) | ((unsigned)f2b(a.y) << 16);
  v.y = (unsigned)f2b(a.z) | ((unsigned)f2b(a.w) << 16);
  v.z = (unsigned)f2b(b.x) | ((unsigned)f2b(b.y) << 16);
  v.w = (unsigned)f2b(b.z) | ((unsigned)f2b(b.w) << 16);
  reinterpret_cast<uint4*>(out)[i] = v;
}

// codebook -> bf16, plus per-row squared L2 norm (fp32, exact)
__global__ void cvt_codebook(const float* __restrict__ cb, u16* __restrict__ cbb,
                             float* __restrict__ cnorm) {
  int k = blockIdx.x;          // 0..4095
  int t = threadIdx.x;         // 0..255
  float c0 = cb[(size_t)k * DIM + t];
  float c1 = cb[(size_t)k * DIM + 256 + t];
  cbb[(size_t)k * DIM + t]       = f2b(c0);
  cbb[(size_t)k * DIM + 256 + t] = f2b(c1);
  float s = c0 * c0 + c1 * c1;
#pragma unroll
  for (int m = 1; m < 64; m <<= 1) s += __shfl_xor(s, m, 64);
  __shared__ float w4[4];
  if ((t & 63) == 0) w4[t >> 6] = s;
  __syncthreads();
  if (t == 0) cnorm[k] = w4[0] + w4[1] + w4[2] + w4[3];
}

// ---------------- argmin GEMM: scores = cnorm[k] - 2 * x.c ------------------
// 256x256 tile, BK=64, 8 waves (2M x 4N), counted-vmcnt 2-tile-deep pipeline
// (T4), per-phase barrier interleave (T3: 4 phases/tile, 16 MFMA each),
// T2 XOR-swizzle, T5 setprio around each MFMA cluster.
__global__ __launch_bounds__(512, 2)
void argmin_gemm8(const u16* __restrict__ Xb, const u16* __restrict__ Cb,
                  const float* __restrict__ cnorm,
                  float* __restrict__ pval, int* __restrict__ pidx) {
  __shared__ u16 As[2][256 * 64];   // 64 KiB
  __shared__ u16 Bs[2][256 * 64];   // 64 KiB  (128 KiB total)

  const int tid  = threadIdx.x;
  const int lane = tid & 63;
  const int wid  = tid >> 6;          // 0..7
  const int wr   = wid >> 2;          // 0..1  (M half)
  const int wc   = wid & 3;           // 0..3  (N quarter)
  const int bm   = blockIdx.x;        // 0..127 token tiles
  const int bn   = blockIdx.y;        // 0..15  code tiles
  const int l15  = lane & 15, l4 = lane >> 4;
  const int srow = lane >> 3;                 // 0..7
  const int sslot = (lane & 7) ^ srow;        // pre-swizzled 16B slot (involution)

  const u16* Xrow = Xb + (size_t)(bm * 256) * DIM;
  const u16* Crow = Cb + (size_t)(bn * 256) * DIM;

  // stage one K-tile (A[256][64] + B[256][64]) -> buf; 8 gload_lds / thread
  auto stage = [&](int buf, int kt) {
    int kk = kt * 64;
#pragma unroll
    for (int j = 0; j < 4; j++) {
      int r = j * 64 + wid * 8 + srow;
      gload_lds16(Xrow + (size_t)r * DIM + kk + sslot * 8,
                  (void*)(As[buf] + (j * 64 + wid * 8) * 64));
      gload_lds16(Crow + (size_t)r * DIM + kk + sslot * 8,
                  (void*)(Bs[buf] + (j * 64 + wid * 8) * 64));
    }
  };

  f32x4 acc[8][4];
#pragma unroll
  for (int i = 0; i < 8; i++)
#pragma unroll
    for (int j = 0; j < 4; j++)
#pragma unroll
      for (int r = 0; r < 4; r++) acc[i][j][r] = 0.f;

  stage(0, 0);
  stage(1, 1);
  asm volatile("s_waitcnt vmcnt(8)" ::: "memory");   // buf0 landed, buf1 in flight
  __builtin_amdgcn_s_barrier();                      // buf0 visible to all waves
  asm volatile("" ::: "memory");

  for (int t = 0; t < 8; ++t) {
    const u16* A  = As[t & 1];
    const u16* Bt = Bs[t & 1];
    bf16x8 bfr[4];   // B fragments for current ks-half (reused across 2 phases)

#pragma unroll
    for (int ph = 0; ph < 4; ph++) {     // phase = (ks-half, mi-half)
      const int ks = ph >> 1;
      const int mh = ph & 1;
      // --- phase reads (issued pre-barrier; land during barrier wait) ---
      if (mh == 0) {
#pragma unroll
        for (int ni = 0; ni < 4; ni++) {
          int row = wc * 64 + ni * 16 + l15;
          int col = (ks * 32 + l4 * 8) ^ ((row & 7) << 3);
          bfr[ni] = *reinterpret_cast<const bf16x8*>(Bt + row * 64 + col);
        }
      }
      bf16x8 af[4];
#pragma unroll
      for (int m = 0; m < 4; m++) {
        int row = wr * 128 + (mh * 4 + m) * 16 + l15;
        int col = (ks * 32 + l4 * 8) ^ ((row & 7) << 3);
        af[m] = *reinterpret_cast<const bf16x8*>(A + row * 64 + col);
      }
      asm volatile("" ::: "memory");
      __builtin_amdgcn_s_barrier();
      asm volatile("s_waitcnt lgkmcnt(0)" ::: "memory");
      __builtin_amdgcn_sched_barrier(0);
      __builtin_amdgcn_s_setprio(1);
#pragma unroll
      for (int m = 0; m < 4; m++)
#pragma unroll
        for (int ni = 0; ni < 4; ni++)
          acc[mh * 4 + m][ni] = __builtin_amdgcn_mfma_f32_16x16x32_bf16(
              af[m], bfr[ni], acc[mh * 4 + m][ni], 0, 0, 0);
      __builtin_amdgcn_s_setprio(0);
      asm volatile("" ::: "memory");
      __builtin_amdgcn_s_barrier();
      asm volatile("" ::: "memory");
    }

    // --- tile boundary: refill freed buffer, counted-vmcnt wait ---
    if (t + 2 < 8) stage(t & 1, t + 2);
    if (t < 7) {
      if (t < 6) asm volatile("s_waitcnt vmcnt(8)" ::: "memory");
      else       asm volatile("s_waitcnt vmcnt(0)" ::: "memory");
      __builtin_amdgcn_s_barrier();      // next buf visible to all waves
      asm volatile("" ::: "memory");
    }
  }

  // ---------------- epilogue: per-token argmin over 256 codes ----------------
  float* rv = (float*)As;   // [4][256] — alias, safe after final barrier
  int*   ri = (int*)Bs;
  __syncthreads();

#pragma unroll
  for (int mi = 0; mi < 8; mi++) {
#pragma unroll
    for (int r = 0; r < 4; r++) {
      float best = 1e30f;
      int bi = 0;
#pragma unroll
      for (int ni = 0; ni < 4; ni++) {
        int code = bn * 256 + wc * 64 + ni * 16 + l15;
        float v = cnorm[code] - 2.0f * acc[mi][ni][r];
        if (v < best) { best = v; bi = code; }
      }
#pragma unroll
      for (int m = 1; m < 16; m <<= 1) {
        float ov = __shfl_xor(best, m, 64);
        int   oi = __shfl_xor(bi, m, 64);
        if (ov < best) { best = ov; bi = oi; }
      }
      if (l15 == 0) {
        int tok = wr * 128 + mi * 16 + l4 * 4 + r;   // 0..255
        rv[wc * 256 + tok] = best;
        ri[wc * 256 + tok] = bi;
      }
    }
  }
  __syncthreads();
  if (tid < 256) {
    float bv = rv[tid];
    int   bb = ri[tid];
#pragma unroll
    for (int c = 1; c < 4; c++) {
      float v = rv[c * 256 + tid];
      if (v < bv) { bv = v; bb = ri[c * 256 + tid]; }
    }
    size_t g = (size_t)bn * NTOK + bm * 256 + tid;
    pval[g] = bv;
    pidx[g] = bb;
  }
}

__global__ void argmin_reduce(const float* __restrict__ pval, const int* __restrict__ pidx,
                              int* __restrict__ idx) {
  int t = blockIdx.x * 256 + threadIdx.x;   // 0..32767
  float best = 1e30f;
  int bi = 0;
  for (int c = 0; c < 16; c++) {
    float v = pval[(size_t)c * NTOK + t];
    if (v < best) { best = v; bi = pidx[(size_t)c * NTOK + t]; }
  }
  idx[t] = bi;
}

// ---------- gate GEMM (X @ W^T) + fused epilogue + deterministic loss -------
__global__ __launch_bounds__(256)
void gate_out(const u16* __restrict__ Xb, const u16* __restrict__ Wb,
              const float* __restrict__ X, const float* __restrict__ Cf,
              const float* __restrict__ gb, const int* __restrict__ idx,
              float* __restrict__ out, float* __restrict__ blockSum) {
  __shared__ u16 As[2][128 * 64];
  __shared__ u16 Bs[2][128 * 64];
  __shared__ float bsum[4];

  const int tid  = threadIdx.x;
  const int lane = tid & 63;
  const int wid  = tid >> 6;
  const int wr   = wid >> 1, wc = wid & 1;
  const int bm   = blockIdx.x;        // 0..255
  const int bn   = blockIdx.y;        // 0..3
  const int l15  = lane & 15, l4 = lane >> 4;
  const int srow = lane >> 3;
  const int scol = (((lane & 7) ^ (lane >> 3)) & 7) * 8;

  const u16* Xrow = Xb + (size_t)(bm * 128) * DIM;
  const u16* Wrow = Wb + (size_t)(bn * 128) * DIM;

  auto stage = [&](int buf, int kk) {
#pragma unroll
    for (int i = 0; i < 4; i++) {
      int rA = (wid * 4 + i) * 8 + srow;
      gload_lds16(Xrow + (size_t)rA * DIM + kk + scol,
                  (void*)(As[buf] + (wid * 4 + i) * 512));
      gload_lds16(Wrow + (size_t)rA * DIM + kk + scol,
                  (void*)(Bs[buf] + (wid * 4 + i) * 512));
    }
  };

  f32x4 acc[4][4];
#pragma unroll
  for (int i = 0; i < 4; i++)
#pragma unroll
    for (int j = 0; j < 4; j++)
#pragma unroll
      for (int r = 0; r < 4; r++) acc[i][j][r] = 0.f;

  stage(0, 0);
  __syncthreads();
  int cur = 0;
  for (int t = 0; t < 8; ++t) {
    if (t < 7) stage(cur ^ 1, (t + 1) * 64);
#pragma unroll
    for (int ks = 0; ks < 2; ks++) {
      bf16x8 af[4], bfr[4];
#pragma unroll
      for (int mi = 0; mi < 4; mi++) {
        int row = wr * 64 + mi * 16 + l15;
        int col = (ks * 32 + l4 * 8) ^ ((row & 7) << 3);
        af[mi] = *reinterpret_cast<const bf16x8*>(As[cur] + row * 64 + col);
      }
#pragma unroll
      for (int ni = 0; ni < 4; ni++) {
        int row = wc * 64 + ni * 16 + l15;
        int col = (ks * 32 + l4 * 8) ^ ((row & 7) << 3);
        bfr[ni] = *reinterpret_cast<const bf16x8*>(Bs[cur] + row * 64 + col);
      }
#pragma unroll
      for (int mi = 0; mi < 4; mi++)
#pragma unroll
        for (int ni = 0; ni < 4; ni++)
          acc[mi][ni] = __builtin_amdgcn_mfma_f32_16x16x32_bf16(
              af[mi], bfr[ni], acc[mi][ni], 0, 0, 0);
    }
    __syncthreads();
    cur ^= 1;
  }

  // epilogue: gate = sigmoid(acc + b), out = x + c[idx]*gate, loss partial
  float lsum = 0.f;
#pragma unroll
  for (int mi = 0; mi < 4; mi++) {
#pragma unroll
    for (int r = 0; r < 4; r++) {
      int token = bm * 128 + wr * 64 + mi * 16 + l4 * 4 + r;
      int code = idx[token];
#pragma unroll
      for (int ni = 0; ni < 4; ni++) {
        int col = bn * 128 + wc * 64 + ni * 16 + l15;
        float logit = acc[mi][ni][r] + gb[col];
        float g = 1.0f / (1.0f + __expf(-logit));
        float q = Cf[(size_t)code * DIM + col];
        float xx = X[(size_t)token * DIM + col];
        out[(size_t)token * DIM + col] = xx + q * g;
        float d = q - xx;
        lsum += d * d;
      }
    }
  }
#pragma unroll
  for (int m = 1; m < 64; m <<= 1) lsum += __shfl_xor(lsum, m, 64);
  if (lane == 0) bsum[wid] = lsum;
  __syncthreads();
  if (tid == 0)
    blockSum[blockIdx.y * gridDim.x + blockIdx.x] = bsum[0] + bsum[1] + bsum[2] + bsum[3];
}

__global__ void finalize(const float* __restrict__ blockSum, float* __restrict__ out_loss) {
  int t = threadIdx.x;  // 256 threads, 1024 partials
  float s = 0.f;
#pragma unroll
  for (int i = 0; i < 4; i++) s += blockSum[t * 4 + i];
#pragma unroll
  for (int m = 1; m < 64; m <<= 1) s += __shfl_xor(s, m, 64);
  __shared__ float w4[4];
  if ((t & 63) == 0) w4[t >> 6] = s;
  __syncthreads();
  if (t == 0) {
    float tot = w4[0] + w4[1] + w4[2] + w4[3];
    out_loss[0] = 1.25f * tot / 16777216.0f;   // N*D = 32768*512
  }
}

extern "C" void kernel_launch(void* const* d_in, const int* in_sizes, int n_in,
                              void* d_out, int out_size, void* d_ws, size_t ws_size,
                              hipStream_t stream) {
  const float* X  = (const float*)d_in[0];   // [32768, 512]
  const float* CB = (const float*)d_in[1];   // [4096, 512]
  const float* GW = (const float*)d_in[2];   // [512, 512]
  const float* GB = (const float*)d_in[3];   // [512]
  float* out = (float*)d_out;                // [32768*512] output + [1] loss

  char* w = (char*)d_ws;
  size_t off = 0;
  auto alloc = [&](size_t bytes) -> void* {
    void* p = w + off;
    off = (off + bytes + 255) & ~(size_t)255;
    return p;
  };
  u16*   Xb    = (u16*)alloc((size_t)NTOK * DIM * 2);   // 33.5 MB
  u16*   Cb    = (u16*)alloc((size_t)KC * DIM * 2);     // 4.2 MB
  u16*   Wb    = (u16*)alloc((size_t)DIM * DIM * 2);    // 0.5 MB
  float* cnorm = (float*)alloc((size_t)KC * 4);
  float* pval  = (float*)alloc((size_t)16 * NTOK * 4);  // 2.1 MB
  int*   pidx  = (int*)alloc((size_t)16 * NTOK * 4);    // 2.1 MB
  int*   idx   = (int*)alloc((size_t)NTOK * 4);
  float* bsums = (float*)alloc((size_t)1024 * 4);

  cvt8<<<8192, 256, 0, stream>>>(X, Xb, NTOK * DIM / 8);
  cvt8<<<128, 256, 0, stream>>>(GW, Wb, DIM * DIM / 8);
  cvt_codebook<<<KC, 256, 0, stream>>>(CB, Cb, cnorm);
  argmin_gemm8<<<dim3(128, 16), 512, 0, stream>>>(Xb, Cb, cnorm, pval, pidx);
  argmin_reduce<<<128, 256, 0, stream>>>(pval, pidx, idx);
  gate_out<<<dim3(256, 4), 256, 0, stream>>>(Xb, Wb, X, CB, GB, idx, out, bsums);
  finalize<<<1, 256, 0, stream>>>(bsums, out + (size_t)NTOK * DIM);
}

// Round 6
// 232.481 us; speedup vs baseline: 1.2206x; 1.2206x over previous
//
#include <hip/hip_runtime.h>
#include <hip/hip_bf16.h>

typedef unsigned short u16;
typedef unsigned char u8;
typedef __bf16 bf16x8 __attribute__((ext_vector_type(8)));
typedef float f32x4 __attribute__((ext_vector_type(4)));

#define NTOK 32768   // B*S = 8*4096
#define DIM  512
#define KC   4096

__device__ __forceinline__ u16 f2b(float f) {
  __hip_bfloat16 h = __float2bfloat16(f);
  return *reinterpret_cast<u16*>(&h);
}

__device__ __forceinline__ void gload_lds16(const void* g, void* l) {
  __builtin_amdgcn_global_load_lds(
      (__attribute__((address_space(1))) void*)g,
      (__attribute__((address_space(3))) void*)l,
      16, 0, 0);
}

// -------- prep: X fp32 -> bf16 (for gate) + fp8 e4m3 (for argmin) ----------
__global__ void cvt_x(const float* __restrict__ in, u16* __restrict__ bf,
                      u8* __restrict__ q, int n8) {
  int i = blockIdx.x * blockDim.x + threadIdx.x;
  if (i >= n8) return;
  const float4* p = reinterpret_cast<const float4*>(in) + 2 * (size_t)i;
  float4 a = p[0], b = p[1];
  uint4 v;
  v.x = (unsigned)f2b(a.x) | ((unsigned)f2b(a.y) << 16);
  v.y = (unsigned)f2b(a.z) | ((unsigned)f2b(a.w) << 16);
  v.z = (unsigned)f2b(b.x) | ((unsigned)f2b(b.y) << 16);
  v.w = (unsigned)f2b(b.z) | ((unsigned)f2b(b.w) << 16);
  reinterpret_cast<uint4*>(bf)[i] = v;
  int u0 = __builtin_amdgcn_cvt_pk_fp8_f32(a.x, a.y, 0, false);
  u0     = __builtin_amdgcn_cvt_pk_fp8_f32(a.z, a.w, u0, true);
  int u1 = __builtin_amdgcn_cvt_pk_fp8_f32(b.x, b.y, 0, false);
  u1     = __builtin_amdgcn_cvt_pk_fp8_f32(b.z, b.w, u1, true);
  uint2 w2; w2.x = (unsigned)u0; w2.y = (unsigned)u1;
  reinterpret_cast<uint2*>(q)[i] = w2;
}

// W fp32 -> bf16 (gate GEMM)
__global__ void cvt8(const float* __restrict__ in, u16* __restrict__ out, int n8) {
  int i = blockIdx.x * blockDim.x + threadIdx.x;
  if (i >= n8) return;
  const float4* p = reinterpret_cast<const float4*>(in) + 2 * (size_t)i;
  float4 a = p[0], b = p[1];
  uint4 v;
  v.x = (unsigned)f2b(a.x) | ((unsigned)f2b(a.y) << 16);
  v.y = (unsigned)f2b(a.z) | ((unsigned)f2b(a.w) << 16);
  v.z = (unsigned)f2b(b.x) | ((unsigned)f2b(b.y) << 16);
  v.w = (unsigned)f2b(b.z) | ((unsigned)f2b(b.w) << 16);
  reinterpret_cast<uint4*>(out)[i] = v;
}

// codebook -> fp8 scaled by 4096 (values in ±1), plus exact fp32 row norms
__global__ void cvt_codebook(const float* __restrict__ cb, u8* __restrict__ cbq,
                             float* __restrict__ cnorm) {
  int k = blockIdx.x;          // 0..4095
  int t = threadIdx.x;         // 0..255, handles elems 2t, 2t+1
  float c0 = cb[(size_t)k * DIM + 2 * t];
  float c1 = cb[(size_t)k * DIM + 2 * t + 1];
  int pk = __builtin_amdgcn_cvt_pk_fp8_f32(c0 * 4096.f, c1 * 4096.f, 0, false);
  *reinterpret_cast<u16*>(cbq + (size_t)k * DIM + 2 * t) = (u16)(pk & 0xffff);
  float s = c0 * c0 + c1 * c1;
#pragma unroll
  for (int m = 1; m < 64; m <<= 1) s += __shfl_xor(s, m, 64);
  __shared__ float w4[4];
  if ((t & 63) == 0) w4[t >> 6] = s;
  __syncthreads();
  if (t == 0) cnorm[k] = w4[0] + w4[1] + w4[2] + w4[3];
}

// ---------------- argmin GEMM (fp8): scores = cnorm[k] - 2 x.c -------------
// 128x256 tile, BK=64, 8 waves (2M x 4N), fp8 e4m3 mfma 16x16x32,
// counted-vmcnt 2-tile-deep, 16B-granular XOR swizzle, 2 blocks/CU target.
__global__ __launch_bounds__(512, 4)
void argmin_fp8(const u8* __restrict__ Xq, const u8* __restrict__ Cq,
                const float* __restrict__ cnorm,
                float* __restrict__ pval, int* __restrict__ pidx) {
  __shared__ u8 As[2][128 * 64];   // 8 KiB each
  __shared__ u8 Bs[2][256 * 64];   // 16 KiB each  (48 KiB total)

  const int tid  = threadIdx.x;
  const int lane = tid & 63;
  const int wid  = tid >> 6;          // 0..7
  const int wr   = wid >> 2;          // 0..1 (M half: 64 rows)
  const int wc   = wid & 3;           // 0..3 (N quarter: 64 cols)
  const int bm   = blockIdx.x;        // 0..255 token tiles (128 each)
  const int bn   = blockIdx.y;        // 0..15  code tiles (256 each)
  const int l15  = lane & 15, l4 = lane >> 4;

  const u8* Xg = Xq + (size_t)(bm * 128) * DIM;
  const u8* Cg = Cq + (size_t)(bn * 256) * DIM;

  // stage one K-tile: A 128x64B (1 pass) + B 256x64B (2 passes) = 3 gloads
  auto stage = [&](int buf, int kt) {
    int kk = kt * 64;
    {
      int row = wid * 16 + (lane >> 2);            // 0..127
      int ss  = (lane & 3) ^ ((row >> 1) & 3);     // pre-swizzled 16B slot
      gload_lds16(Xg + (size_t)row * DIM + kk + ss * 16,
                  (void*)(As[buf] + wid * 1024));
    }
#pragma unroll
    for (int p = 0; p < 2; p++) {
      int row = p * 128 + wid * 16 + (lane >> 2);  // 0..255
      int ss  = (lane & 3) ^ ((row >> 1) & 3);
      gload_lds16(Cg + (size_t)row * DIM + kk + ss * 16,
                  (void*)(Bs[buf] + p * 8192 + wid * 1024));
    }
  };

  // swizzled 8-byte fragment read: s8 = 8B slot 0..7 within the 64B row
  auto rd8 = [&](const u8* base, int row, int s8) -> long long {
    int addr = row * 64 + ((((s8 >> 1) ^ ((row >> 1) & 3)) << 4)) + ((s8 & 1) << 3);
    return *reinterpret_cast<const long long*>(base + addr);
  };

  f32x4 acc[4][4];
#pragma unroll
  for (int i = 0; i < 4; i++)
#pragma unroll
    for (int j = 0; j < 4; j++)
#pragma unroll
      for (int r = 0; r < 4; r++) acc[i][j][r] = 0.f;

  stage(0, 0);
  stage(1, 1);
  asm volatile("s_waitcnt vmcnt(3)" ::: "memory");   // tile0's 3 landed
  __builtin_amdgcn_s_barrier();
  asm volatile("" ::: "memory");

  for (int t = 0; t < 8; ++t) {
    const u8* A  = As[t & 1];
    const u8* Bt = Bs[t & 1];
    long long bfr[4][2];
#pragma unroll
    for (int ni = 0; ni < 4; ni++)
#pragma unroll
      for (int ks = 0; ks < 2; ks++)
        bfr[ni][ks] = rd8(Bt, wc * 64 + ni * 16 + l15, ks * 4 + l4);
#pragma unroll
    for (int mi = 0; mi < 4; mi++) {
      long long af0 = rd8(A, wr * 64 + mi * 16 + l15, l4);
      long long af1 = rd8(A, wr * 64 + mi * 16 + l15, 4 + l4);
      __builtin_amdgcn_s_setprio(1);
#pragma unroll
      for (int ni = 0; ni < 4; ni++) {
        acc[mi][ni] = __builtin_amdgcn_mfma_f32_16x16x32_fp8_fp8(
            af0, bfr[ni][0], acc[mi][ni], 0, 0, 0);
        acc[mi][ni] = __builtin_amdgcn_mfma_f32_16x16x32_fp8_fp8(
            af1, bfr[ni][1], acc[mi][ni], 0, 0, 0);
      }
      __builtin_amdgcn_s_setprio(0);
    }

    asm volatile("" ::: "memory");
    __builtin_amdgcn_s_barrier();          // all waves done reading buf[t&1]
    asm volatile("" ::: "memory");
    if (t + 2 < 8) {
      stage(t & 1, t + 2);                 // refill freed buffer (3 loads)
      asm volatile("s_waitcnt vmcnt(3)" ::: "memory");   // tile t+1 landed
      __builtin_amdgcn_s_barrier();
      asm volatile("" ::: "memory");
    } else if (t < 7) {
      asm volatile("s_waitcnt vmcnt(0)" ::: "memory");
      __builtin_amdgcn_s_barrier();
      asm volatile("" ::: "memory");
    }
  }

  // -------- epilogue: per-token argmin over this block's 256 codes ---------
  // scores = cnorm - (2/4096) * acc   (codebook was pre-scaled by 4096)
  const float SC = 4.8828125e-4f;   // 2^-11
  float* rv = (float*)As;   // [4][128]
  int*   ri = (int*)Bs;
  __syncthreads();

#pragma unroll
  for (int mi = 0; mi < 4; mi++) {
#pragma unroll
    for (int r = 0; r < 4; r++) {
      float best = 1e30f;
      int bi = 0;
#pragma unroll
      for (int ni = 0; ni < 4; ni++) {
        int code = bn * 256 + wc * 64 + ni * 16 + l15;
        float v = cnorm[code] - SC * acc[mi][ni][r];
        if (v < best) { best = v; bi = code; }
      }
#pragma unroll
      for (int m = 1; m < 16; m <<= 1) {
        float ov = __shfl_xor(best, m, 64);
        int   oi = __shfl_xor(bi, m, 64);
        if (ov < best) { best = ov; bi = oi; }
      }
      if (l15 == 0) {
        int tok = wr * 64 + mi * 16 + l4 * 4 + r;   // 0..127
        rv[wc * 128 + tok] = best;
        ri[wc * 128 + tok] = bi;
      }
    }
  }
  __syncthreads();
  if (tid < 128) {
    float bv = rv[tid];
    int   bb = ri[tid];
#pragma unroll
    for (int c = 1; c < 4; c++) {
      float v = rv[c * 128 + tid];
      if (v < bv) { bv = v; bb = ri[c * 128 + tid]; }
    }
    size_t g = (size_t)bn * NTOK + bm * 128 + tid;
    pval[g] = bv;
    pidx[g] = bb;
  }
}

__global__ void argmin_reduce(const float* __restrict__ pval, const int* __restrict__ pidx,
                              int* __restrict__ idx) {
  int t = blockIdx.x * 256 + threadIdx.x;   // 0..32767
  float best = 1e30f;
  int bi = 0;
  for (int c = 0; c < 16; c++) {
    float v = pval[(size_t)c * NTOK + t];
    if (v < best) { best = v; bi = pidx[(size_t)c * NTOK + t]; }
  }
  idx[t] = bi;
}

// ---------- gate GEMM (X @ W^T) + fused epilogue + deterministic loss -------
__global__ __launch_bounds__(256)
void gate_out(const u16* __restrict__ Xb, const u16* __restrict__ Wb,
              const float* __restrict__ X, const float* __restrict__ Cf,
              const float* __restrict__ gb, const int* __restrict__ idx,
              float* __restrict__ out, float* __restrict__ blockSum) {
  __shared__ u16 As[2][128 * 64];
  __shared__ u16 Bs[2][128 * 64];
  __shared__ float bsum[4];

  const int tid  = threadIdx.x;
  const int lane = tid & 63;
  const int wid  = tid >> 6;
  const int wr   = wid >> 1, wc = wid & 1;
  const int bm   = blockIdx.x;        // 0..255
  const int bn   = blockIdx.y;        // 0..3
  const int l15  = lane & 15, l4 = lane >> 4;
  const int srow = lane >> 3;
  const int scol = (((lane & 7) ^ (lane >> 3)) & 7) * 8;

  const u16* Xrow = Xb + (size_t)(bm * 128) * DIM;
  const u16* Wrow = Wb + (size_t)(bn * 128) * DIM;

  auto stage = [&](int buf, int kk) {
#pragma unroll
    for (int i = 0; i < 4; i++) {
      int rA = (wid * 4 + i) * 8 + srow;
      gload_lds16(Xrow + (size_t)rA * DIM + kk + scol,
                  (void*)(As[buf] + (wid * 4 + i) * 512));
      gload_lds16(Wrow + (size_t)rA * DIM + kk + scol,
                  (void*)(Bs[buf] + (wid * 4 + i) * 512));
    }
  };

  f32x4 acc[4][4];
#pragma unroll
  for (int i = 0; i < 4; i++)
#pragma unroll
    for (int j = 0; j < 4; j++)
#pragma unroll
      for (int r = 0; r < 4; r++) acc[i][j][r] = 0.f;

  stage(0, 0);
  __syncthreads();
  int cur = 0;
  for (int t = 0; t < 8; ++t) {
    if (t < 7) stage(cur ^ 1, (t + 1) * 64);
#pragma unroll
    for (int ks = 0; ks < 2; ks++) {
      bf16x8 af[4], bfr[4];
#pragma unroll
      for (int mi = 0; mi < 4; mi++) {
        int row = wr * 64 + mi * 16 + l15;
        int col = (ks * 32 + l4 * 8) ^ ((row & 7) << 3);
        af[mi] = *reinterpret_cast<const bf16x8*>(As[cur] + row * 64 + col);
      }
#pragma unroll
      for (int ni = 0; ni < 4; ni++) {
        int row = wc * 64 + ni * 16 + l15;
        int col = (ks * 32 + l4 * 8) ^ ((row & 7) << 3);
        bfr[ni] = *reinterpret_cast<const bf16x8*>(Bs[cur] + row * 64 + col);
      }
#pragma unroll
      for (int mi = 0; mi < 4; mi++)
#pragma unroll
        for (int ni = 0; ni < 4; ni++)
          acc[mi][ni] = __builtin_amdgcn_mfma_f32_16x16x32_bf16(
              af[mi], bfr[ni], acc[mi][ni], 0, 0, 0);
    }
    __syncthreads();
    cur ^= 1;
  }

  // epilogue: gate = sigmoid(acc + b), out = x + c[idx]*gate, loss partial
  float lsum = 0.f;
#pragma unroll
  for (int mi = 0; mi < 4; mi++) {
#pragma unroll
    for (int r = 0; r < 4; r++) {
      int token = bm * 128 + wr * 64 + mi * 16 + l4 * 4 + r;
      int code = idx[token];
#pragma unroll
      for (int ni = 0; ni < 4; ni++) {
        int col = bn * 128 + wc * 64 + ni * 16 + l15;
        float logit = acc[mi][ni][r] + gb[col];
        float g = 1.0f / (1.0f + __expf(-logit));
        float q = Cf[(size_t)code * DIM + col];
        float xx = X[(size_t)token * DIM + col];
        out[(size_t)token * DIM + col] = xx + q * g;
        float d = q - xx;
        lsum += d * d;
      }
    }
  }
#pragma unroll
  for (int m = 1; m < 64; m <<= 1) lsum += __shfl_xor(lsum, m, 64);
  if (lane == 0) bsum[wid] = lsum;
  __syncthreads();
  if (tid == 0)
    blockSum[blockIdx.y * gridDim.x + blockIdx.x] = bsum[0] + bsum[1] + bsum[2] + bsum[3];
}

__global__ void finalize(const float* __restrict__ blockSum, float* __restrict__ out_loss) {
  int t = threadIdx.x;  // 256 threads, 1024 partials
  float s = 0.f;
#pragma unroll
  for (int i = 0; i < 4; i++) s += blockSum[t * 4 + i];
#pragma unroll
  for (int m = 1; m < 64; m <<= 1) s += __shfl_xor(s, m, 64);
  __shared__ float w4[4];
  if ((t & 63) == 0) w4[t >> 6] = s;
  __syncthreads();
  if (t == 0) {
    float tot = w4[0] + w4[1] + w4[2] + w4[3];
    out_loss[0] = 1.25f * tot / 16777216.0f;   // N*D = 32768*512
  }
}

extern "C" void kernel_launch(void* const* d_in, const int* in_sizes, int n_in,
                              void* d_out, int out_size, void* d_ws, size_t ws_size,
                              hipStream_t stream) {
  const float* X  = (const float*)d_in[0];   // [32768, 512]
  const float* CB = (const float*)d_in[1];   // [4096, 512]
  const float* GW = (const float*)d_in[2];   // [512, 512]
  const float* GB = (const float*)d_in[3];   // [512]
  float* out = (float*)d_out;                // [32768*512] output + [1] loss

  char* w = (char*)d_ws;
  size_t off = 0;
  auto alloc = [&](size_t bytes) -> void* {
    void* p = w + off;
    off = (off + bytes + 255) & ~(size_t)255;
    return p;
  };
  u16*   Xb    = (u16*)alloc((size_t)NTOK * DIM * 2);   // 33.5 MB (gate)
  u8*    Xq    = (u8*) alloc((size_t)NTOK * DIM);       // 16.8 MB (argmin)
  u8*    Cq    = (u8*) alloc((size_t)KC * DIM);         // 2.1 MB (argmin, x4096)
  u16*   Wb    = (u16*)alloc((size_t)DIM * DIM * 2);    // 0.5 MB
  float* cnorm = (float*)alloc((size_t)KC * 4);
  float* pval  = (float*)alloc((size_t)16 * NTOK * 4);  // 2.1 MB
  int*   pidx  = (int*)alloc((size_t)16 * NTOK * 4);    // 2.1 MB
  int*   idx   = (int*)alloc((size_t)NTOK * 4);
  float* bsums = (float*)alloc((size_t)1024 * 4);

  cvt_x<<<8192, 256, 0, stream>>>(X, Xb, Xq, NTOK * DIM / 8);
  cvt8<<<128, 256, 0, stream>>>(GW, Wb, DIM * DIM / 8);
  cvt_codebook<<<KC, 256, 0, stream>>>(CB, Cq, cnorm);
  argmin_fp8<<<dim3(256, 16), 512, 0, stream>>>(Xq, Cq, cnorm, pval, pidx);
  argmin_reduce<<<128, 256, 0, stream>>>(pval, pidx, idx);
  gate_out<<<dim3(256, 4), 256, 0, stream>>>(Xb, Wb, X, CB, GB, idx, out, bsums);
  finalize<<<1, 256, 0, stream>>>(bsums, out + (size_t)NTOK * DIM);
}